// Round 10
// baseline (435.177 us; speedup 1.0000x reference)
//
#include <hip/hip_runtime.h>
#include <hip/hip_bf16.h>
#include <hip/hip_cooperative_groups.h>

namespace cg = cooperative_groups;

#define N_NODES 50000
#define N_EDGES 800000
#define SCAN_B 256
#define SCAN_NB ((N_NODES + SCAN_B - 1) / SCAN_B)  // 196

typedef __attribute__((ext_vector_type(8))) short bf16x8;
typedef __attribute__((ext_vector_type(4))) float f32x4;

__device__ __forceinline__ float bf2f(unsigned short u) {
    unsigned int x = ((unsigned int)u) << 16;
    return __uint_as_float(x);
}
__device__ __forceinline__ unsigned short f2bf(float f) {
    unsigned int x = __float_as_uint(f);
    unsigned int lsb = (x >> 16) & 1u;
    x += 0x7fffu + lsb;
    return (unsigned short)(x >> 16);
}

// ---------------- CSR build: ONE cooperative kernel, R6-proven phase logic ----------------
// 196 blocks x 256 (co-resident; == SCAN_NB so scan phases keep their block mapping).
// Phases separated by grid.sync(); deg/scatter grid-stride over 800k edges.
__global__ __launch_bounds__(256) void k_csr(const int* __restrict__ src,
                                             const int* __restrict__ dst,
                                             int* __restrict__ deg,
                                             int* __restrict__ pos,
                                             int* __restrict__ offsets,
                                             float* __restrict__ inv_deg,
                                             int* __restrict__ blocksum,
                                             int* __restrict__ blockoff,
                                             int* __restrict__ edge_src) {
    cg::grid_group grid = cg::this_grid();
    const int tid = threadIdx.x;
    const int bid = blockIdx.x;
    const int gtid = bid * 256 + tid;
    const int GT = SCAN_NB * 256;  // 50176

    // phase 0: zero deg
    for (int i = gtid; i < N_NODES; i += GT) deg[i] = 0;
    grid.sync();

    // phase 1: degree histogram
    for (int e = gtid; e < N_EDGES; e += GT) atomicAdd(&deg[dst[e]], 1);
    grid.sync();

    // phase 2 (scan1): per-block sums
    {
        int i = bid * SCAN_B + tid;
        int v = (i < N_NODES) ? deg[i] : 0;
        #pragma unroll
        for (int d = 1; d < 64; d <<= 1) v += __shfl_xor(v, d);
        __shared__ int ws1[SCAN_B / 64];
        int wv = tid >> 6, lane = tid & 63;
        if (lane == 0) ws1[wv] = v;
        __syncthreads();
        if (tid == 0) blocksum[bid] = ws1[0] + ws1[1] + ws1[2] + ws1[3];
    }
    grid.sync();

    // phase 3 (scan2): block 0 scans the 196 block sums
    if (bid == 0) {
        __shared__ int buf[SCAN_B];
        int v = (tid < SCAN_NB) ? blocksum[tid] : 0;
        buf[tid] = v;
        __syncthreads();
        for (int off = 1; off < SCAN_B; off <<= 1) {
            int t = (tid >= off) ? buf[tid - off] : 0;
            __syncthreads();
            buf[tid] += t;
            __syncthreads();
        }
        if (tid < SCAN_NB) blockoff[tid] = buf[tid] - v;  // exclusive
        if (tid == 0) offsets[N_NODES] = N_EDGES;
    }
    grid.sync();

    // phase 4 (scan3): per-block local scan -> offsets/pos/inv_deg
    {
        int i = bid * SCAN_B + tid;
        int v = (i < N_NODES) ? deg[i] : 0;
        int lane = tid & 63, wv = tid >> 6;
        int s = v;
        #pragma unroll
        for (int d = 1; d < 64; d <<= 1) {
            int t = __shfl_up(s, d);
            if (lane >= d) s += t;
        }
        __shared__ int ws3[SCAN_B / 64];
        if (lane == 63) ws3[wv] = s;
        __syncthreads();
        int add = 0;
        #pragma unroll
        for (int w = 0; w < SCAN_B / 64; ++w)
            if (w < wv) add += ws3[w];
        int excl = blockoff[bid] + s + add - v;
        if (i < N_NODES) {
            offsets[i] = excl;
            pos[i] = excl;
            inv_deg[i] = 1.0f / (float)max(v, 1);
        }
    }
    grid.sync();

    // phase 5: scatter (dst L2-hot from phase 1)
    for (int e = gtid; e < N_EDGES; e += GT) {
        int p = atomicAdd(&pos[dst[e]], 1);
        edge_src[p] = src[e];
    }
}

// ---------------- prep: W fragment packing (3 layers) + feature f2bf, ONE launch ----------------
// blocks [0,16): layer0 frag, [16,32): layer1, [32,40): layer2, [40,12540): f2bf.
__global__ __launch_bounds__(256) void k_prep(
        const float* __restrict__ Ws0, const float* __restrict__ Wn0,
        const float* __restrict__ Ws1, const float* __restrict__ Wn1,
        const float* __restrict__ Ws2, const float* __restrict__ Wn2,
        __hip_bfloat16* __restrict__ frag0, __hip_bfloat16* __restrict__ frag1,
        __hip_bfloat16* __restrict__ frag2,
        const float2* __restrict__ fin, unsigned int* __restrict__ fout, int n2) {
    int b = blockIdx.x;
    if (b >= 40) {
        int i = (b - 40) * 256 + threadIdx.x;
        if (i < n2) {
            float2 v = fin[i];
            fout[i] = ((unsigned int)f2bf(v.y) << 16) | (unsigned int)f2bf(v.x);
        }
        return;
    }
    const float* Wself;
    const float* Wneigh;
    __hip_bfloat16* frag;
    int Dout, lb;
    if (b < 16)      { Wself = Ws0; Wneigh = Wn0; frag = frag0; Dout = 128; lb = b; }
    else if (b < 32) { Wself = Ws1; Wneigh = Wn1; frag = frag1; Dout = 128; lb = b - 16; }
    else             { Wself = Ws2; Wneigh = Wn2; frag = frag2; Dout = 64;  lb = b - 32; }
    int t = lb * 256 + threadIdx.x;
    int nCt = Dout >> 4;
    int total = nCt * 8 * 64;
    if (t >= total) return;
    int lane = t & 63;
    int kt = (t >> 6) & 7;
    int ct = t >> 9;
    int q = lane >> 4;
    int n = ct * 16 + (lane & 15);
    unsigned short* dstp = (unsigned short*)frag + ((size_t)((ct * 8 + kt) * 64 + lane)) * 8;
    #pragma unroll
    for (int j = 0; j < 8; ++j) {
        int k = kt * 32 + q * 8 + j;
        float v = (k < 128) ? Wself[k * Dout + n] : Wneigh[(k - 128) * Dout + n];
        dstp[j] = f2bf(v);
    }
}

// ---------------- mean aggregation (one wave per node, half-wave edge pairs) ----------------
// h: [N,128] bf16. half=lane>>5 picks edge parity, sub=lane&31 owns cols [4*sub..4*sub+3]
// via one dwordx2. Main loop: 16 edges/iter, 8 independent 8B gathers in flight per lane.
// At the scattered-gather pipe ceiling (~2.3 TB/s L2-miss service) — deeper MLP neutral (R8).
__global__ void k_agg(const __hip_bfloat16* __restrict__ hv, const int* __restrict__ offsets,
                      const int* __restrict__ edge_src, const float* __restrict__ inv_deg,
                      __hip_bfloat16* __restrict__ msg) {
    int gid = blockIdx.x * blockDim.x + threadIdx.x;
    int node = gid >> 6;
    int lane = gid & 63;
    if (node >= N_NODES) return;
    int half = lane >> 5;
    int sub = lane & 31;
    int beg = offsets[node], end = offsets[node + 1];
    const uint2* hp = (const uint2*)hv;  // 32 uint2 per row

    float acc[4][4];
    #pragma unroll
    for (int g = 0; g < 4; ++g)
        #pragma unroll
        for (int c = 0; c < 4; ++c) acc[g][c] = 0.f;

    int i = beg;
    for (; i + 16 <= end; i += 16) {
        int s0 = edge_src[i + half];
        int s1 = edge_src[i + 2 + half];
        int s2 = edge_src[i + 4 + half];
        int s3 = edge_src[i + 6 + half];
        int s4 = edge_src[i + 8 + half];
        int s5 = edge_src[i + 10 + half];
        int s6 = edge_src[i + 12 + half];
        int s7 = edge_src[i + 14 + half];
        uint2 u0 = hp[(size_t)s0 * 32 + sub];
        uint2 u1 = hp[(size_t)s1 * 32 + sub];
        uint2 u2 = hp[(size_t)s2 * 32 + sub];
        uint2 u3 = hp[(size_t)s3 * 32 + sub];
        uint2 u4 = hp[(size_t)s4 * 32 + sub];
        uint2 u5 = hp[(size_t)s5 * 32 + sub];
        uint2 u6 = hp[(size_t)s6 * 32 + sub];
        uint2 u7 = hp[(size_t)s7 * 32 + sub];
        acc[0][0] += bf2f((unsigned short)(u0.x & 0xffffu)); acc[0][1] += bf2f((unsigned short)(u0.x >> 16));
        acc[0][2] += bf2f((unsigned short)(u0.y & 0xffffu)); acc[0][3] += bf2f((unsigned short)(u0.y >> 16));
        acc[1][0] += bf2f((unsigned short)(u1.x & 0xffffu)); acc[1][1] += bf2f((unsigned short)(u1.x >> 16));
        acc[1][2] += bf2f((unsigned short)(u1.y & 0xffffu)); acc[1][3] += bf2f((unsigned short)(u1.y >> 16));
        acc[2][0] += bf2f((unsigned short)(u2.x & 0xffffu)); acc[2][1] += bf2f((unsigned short)(u2.x >> 16));
        acc[2][2] += bf2f((unsigned short)(u2.y & 0xffffu)); acc[2][3] += bf2f((unsigned short)(u2.y >> 16));
        acc[3][0] += bf2f((unsigned short)(u3.x & 0xffffu)); acc[3][1] += bf2f((unsigned short)(u3.x >> 16));
        acc[3][2] += bf2f((unsigned short)(u3.y & 0xffffu)); acc[3][3] += bf2f((unsigned short)(u3.y >> 16));
        acc[0][0] += bf2f((unsigned short)(u4.x & 0xffffu)); acc[0][1] += bf2f((unsigned short)(u4.x >> 16));
        acc[0][2] += bf2f((unsigned short)(u4.y & 0xffffu)); acc[0][3] += bf2f((unsigned short)(u4.y >> 16));
        acc[1][0] += bf2f((unsigned short)(u5.x & 0xffffu)); acc[1][1] += bf2f((unsigned short)(u5.x >> 16));
        acc[1][2] += bf2f((unsigned short)(u5.y & 0xffffu)); acc[1][3] += bf2f((unsigned short)(u5.y >> 16));
        acc[2][0] += bf2f((unsigned short)(u6.x & 0xffffu)); acc[2][1] += bf2f((unsigned short)(u6.x >> 16));
        acc[2][2] += bf2f((unsigned short)(u6.y & 0xffffu)); acc[2][3] += bf2f((unsigned short)(u6.y >> 16));
        acc[3][0] += bf2f((unsigned short)(u7.x & 0xffffu)); acc[3][1] += bf2f((unsigned short)(u7.x >> 16));
        acc[3][2] += bf2f((unsigned short)(u7.y & 0xffffu)); acc[3][3] += bf2f((unsigned short)(u7.y >> 16));
    }
    for (; i + 8 <= end; i += 8) {
        int s0 = edge_src[i + half];
        int s1 = edge_src[i + 2 + half];
        int s2 = edge_src[i + 4 + half];
        int s3 = edge_src[i + 6 + half];
        uint2 u0 = hp[(size_t)s0 * 32 + sub];
        uint2 u1 = hp[(size_t)s1 * 32 + sub];
        uint2 u2 = hp[(size_t)s2 * 32 + sub];
        uint2 u3 = hp[(size_t)s3 * 32 + sub];
        acc[0][0] += bf2f((unsigned short)(u0.x & 0xffffu)); acc[0][1] += bf2f((unsigned short)(u0.x >> 16));
        acc[0][2] += bf2f((unsigned short)(u0.y & 0xffffu)); acc[0][3] += bf2f((unsigned short)(u0.y >> 16));
        acc[1][0] += bf2f((unsigned short)(u1.x & 0xffffu)); acc[1][1] += bf2f((unsigned short)(u1.x >> 16));
        acc[1][2] += bf2f((unsigned short)(u1.y & 0xffffu)); acc[1][3] += bf2f((unsigned short)(u1.y >> 16));
        acc[2][0] += bf2f((unsigned short)(u2.x & 0xffffu)); acc[2][1] += bf2f((unsigned short)(u2.x >> 16));
        acc[2][2] += bf2f((unsigned short)(u2.y & 0xffffu)); acc[2][3] += bf2f((unsigned short)(u2.y >> 16));
        acc[3][0] += bf2f((unsigned short)(u3.x & 0xffffu)); acc[3][1] += bf2f((unsigned short)(u3.x >> 16));
        acc[3][2] += bf2f((unsigned short)(u3.y & 0xffffu)); acc[3][3] += bf2f((unsigned short)(u3.y >> 16));
    }
    for (; i + 4 <= end; i += 4) {
        int s0 = edge_src[i + half];
        int s1 = edge_src[i + 2 + half];
        uint2 u0 = hp[(size_t)s0 * 32 + sub];
        uint2 u1 = hp[(size_t)s1 * 32 + sub];
        acc[0][0] += bf2f((unsigned short)(u0.x & 0xffffu)); acc[0][1] += bf2f((unsigned short)(u0.x >> 16));
        acc[0][2] += bf2f((unsigned short)(u0.y & 0xffffu)); acc[0][3] += bf2f((unsigned short)(u0.y >> 16));
        acc[1][0] += bf2f((unsigned short)(u1.x & 0xffffu)); acc[1][1] += bf2f((unsigned short)(u1.x >> 16));
        acc[1][2] += bf2f((unsigned short)(u1.y & 0xffffu)); acc[1][3] += bf2f((unsigned short)(u1.y >> 16));
    }
    for (; i + 2 <= end; i += 2) {
        int s0 = edge_src[i + half];
        uint2 u0 = hp[(size_t)s0 * 32 + sub];
        acc[0][0] += bf2f((unsigned short)(u0.x & 0xffffu)); acc[0][1] += bf2f((unsigned short)(u0.x >> 16));
        acc[0][2] += bf2f((unsigned short)(u0.y & 0xffffu)); acc[0][3] += bf2f((unsigned short)(u0.y >> 16));
    }
    if (i < end && half == 0) {  // odd leftover: half 0 only
        int s0 = edge_src[i];
        uint2 u0 = hp[(size_t)s0 * 32 + sub];
        acc[0][0] += bf2f((unsigned short)(u0.x & 0xffffu)); acc[0][1] += bf2f((unsigned short)(u0.x >> 16));
        acc[0][2] += bf2f((unsigned short)(u0.y & 0xffffu)); acc[0][3] += bf2f((unsigned short)(u0.y >> 16));
    }

    float r0 = acc[0][0] + acc[1][0] + acc[2][0] + acc[3][0];
    float r1 = acc[0][1] + acc[1][1] + acc[2][1] + acc[3][1];
    float r2 = acc[0][2] + acc[1][2] + acc[2][2] + acc[3][2];
    float r3 = acc[0][3] + acc[1][3] + acc[2][3] + acc[3][3];
    r0 += __shfl_xor(r0, 32);
    r1 += __shfl_xor(r1, 32);
    r2 += __shfl_xor(r2, 32);
    r3 += __shfl_xor(r3, 32);
    if (half == 0) {
        float w = inv_deg[node];
        uint2 o;
        o.x = ((unsigned int)f2bf(r1 * w) << 16) | (unsigned int)f2bf(r0 * w);
        o.y = ((unsigned int)f2bf(r3 * w) << 16) | (unsigned int)f2bf(r2 * w);
        ((uint2*)msg)[(size_t)node * 32 + sub] = o;
    }
}

// ---------------- fused GEMM + bias (+ relu + l2norm) ----------------
template <int NCT, bool LAST>
__global__ __launch_bounds__(256) void k_gemm(const __hip_bfloat16* __restrict__ Aself,
                                              const __hip_bfloat16* __restrict__ Aneigh,
                                              const __hip_bfloat16* __restrict__ frag,
                                              const float* __restrict__ bias,
                                              void* __restrict__ out_) {
    constexpr int Dout = NCT * 16;
    int tid = threadIdx.x;
    int wv = tid >> 6, lane = tid & 63;
    int n0 = blockIdx.x * 64 + wv * 16;
    if (n0 >= N_NODES) return;  // wave-uniform early exit, no LDS used
    int q = lane >> 4, l15 = lane & 15;
    int rowA = n0 + l15;
    if (rowA > N_NODES - 1) rowA = N_NODES - 1;  // clamp loads; stores guarded below

    f32x4 acc[NCT];
    #pragma unroll
    for (int c = 0; c < NCT; ++c) acc[c] = (f32x4){0.f, 0.f, 0.f, 0.f};

    const bf16x8* fragv = (const bf16x8*)frag;
    #pragma unroll
    for (int kt = 0; kt < 8; ++kt) {
        int kb = (kt & 3) * 32 + q * 8;
        const __hip_bfloat16* Ab = (kt < 4) ? Aself : Aneigh;
        bf16x8 a = *(const bf16x8*)(Ab + (size_t)rowA * 128 + kb);
        #pragma unroll
        for (int ct = 0; ct < NCT; ++ct) {
            bf16x8 b = fragv[(ct * 8 + kt) * 64 + lane];
            acc[ct] = __builtin_amdgcn_mfma_f32_16x16x32_bf16(a, b, acc[ct], 0, 0, 0);
        }
    }

    float ss[4] = {0.f, 0.f, 0.f, 0.f};
    #pragma unroll
    for (int ct = 0; ct < NCT; ++ct) {
        float bc = bias[ct * 16 + l15];
        #pragma unroll
        for (int r = 0; r < 4; ++r) {
            float v = acc[ct][r] + bc;
            if (!LAST) v = fmaxf(v, 0.0f);
            acc[ct][r] = v;
            ss[r] += v * v;
        }
    }

    float scale[4];
    #pragma unroll
    for (int r = 0; r < 4; ++r) {
        if (!LAST) {
            float s = ss[r];
            s += __shfl_xor(s, 1);
            s += __shfl_xor(s, 2);
            s += __shfl_xor(s, 4);
            s += __shfl_xor(s, 8);
            scale[r] = 1.0f / fmaxf(sqrtf(s), 1e-12f);
        } else {
            scale[r] = 1.0f;
        }
    }

    #pragma unroll
    for (int ct = 0; ct < NCT; ++ct) {
        #pragma unroll
        for (int r = 0; r < 4; ++r) {
            int row = n0 + q * 4 + r;
            if (row < N_NODES) {
                float v = acc[ct][r] * scale[r];
                if (LAST)
                    ((float*)out_)[(size_t)row * Dout + ct * 16 + l15] = v;
                else
                    ((unsigned short*)out_)[(size_t)row * Dout + ct * 16 + l15] = f2bf(v);
            }
        }
    }
}

// ---------------- host launch ----------------

extern "C" void kernel_launch(void* const* d_in, const int* in_sizes, int n_in,
                              void* d_out, int out_size, void* d_ws, size_t ws_size,
                              hipStream_t stream) {
    const float* features = (const float*)d_in[0];
    const int* src = (const int*)d_in[1];
    const int* dst = (const int*)d_in[2];
    const float* Ws0 = (const float*)d_in[3];
    const float* Wn0 = (const float*)d_in[4];
    const float* b0  = (const float*)d_in[5];
    const float* Ws1 = (const float*)d_in[6];
    const float* Wn1 = (const float*)d_in[7];
    const float* b1  = (const float*)d_in[8];
    const float* Ws2 = (const float*)d_in[9];
    const float* Wn2 = (const float*)d_in[10];
    const float* b2  = (const float*)d_in[11];
    float* out = (float*)d_out;

    char* ws = (char*)d_ws;
    size_t off = 0;
    auto alloc = [&](size_t bytes) -> void* {
        void* p = ws + off;
        off = (off + bytes + 255) & ~(size_t)255;
        return p;
    };
    int*   deg      = (int*)alloc((size_t)N_NODES * 4);
    int*   pos      = (int*)alloc((size_t)N_NODES * 4);
    int*   offs     = (int*)alloc((size_t)(N_NODES + 1) * 4);
    int*   edge_src = (int*)alloc((size_t)N_EDGES * 4);
    float* inv_deg  = (float*)alloc((size_t)N_NODES * 4);
    int*   blocksum = (int*)alloc((size_t)SCAN_NB * 4);
    int*   blockoff = (int*)alloc((size_t)SCAN_NB * 4);
    __hip_bfloat16* fbf = (__hip_bfloat16*)alloc((size_t)N_NODES * 128 * 2);
    __hip_bfloat16* msg = (__hip_bfloat16*)alloc((size_t)N_NODES * 128 * 2);
    __hip_bfloat16* h1  = (__hip_bfloat16*)alloc((size_t)N_NODES * 128 * 2);
    __hip_bfloat16* h2  = (__hip_bfloat16*)alloc((size_t)N_NODES * 128 * 2);
    __hip_bfloat16* frag0 = (__hip_bfloat16*)alloc((size_t)8 * 8 * 64 * 8 * 2);
    __hip_bfloat16* frag1 = (__hip_bfloat16*)alloc((size_t)8 * 8 * 64 * 8 * 2);
    __hip_bfloat16* frag2 = (__hip_bfloat16*)alloc((size_t)4 * 8 * 64 * 8 * 2);

    // CSR build: one cooperative dispatch (R6 phase logic + grid.sync)
    {
        void* args[] = {(void*)&src, (void*)&dst, (void*)&deg, (void*)&pos,
                        (void*)&offs, (void*)&inv_deg, (void*)&blocksum,
                        (void*)&blockoff, (void*)&edge_src};
        hipLaunchCooperativeKernel((const void*)k_csr, dim3(SCAN_NB), dim3(SCAN_B),
                                   args, 0, stream);
    }

    // prep: W fragments (3 layers) + features->bf16, one launch
    const int n2 = N_NODES * 128 / 2;
    const float2* fin = (const float2*)features;
    unsigned int* fout = (unsigned int*)fbf;
    k_prep<<<40 + (n2 + 255) / 256, 256, 0, stream>>>(Ws0, Wn0, Ws1, Wn1, Ws2, Wn2,
                                                      frag0, frag1, frag2, fin, fout, n2);

    const int aggGrid = (N_NODES * 64) / 256;  // 12500
    const int gemmGrid = (N_NODES + 63) / 64;  // 782

    // Layer 1
    k_agg<<<aggGrid, 256, 0, stream>>>(fbf, offs, edge_src, inv_deg, msg);
    k_gemm<8, false><<<gemmGrid, 256, 0, stream>>>(fbf, msg, frag0, b0, h1);
    // Layer 2
    k_agg<<<aggGrid, 256, 0, stream>>>(h1, offs, edge_src, inv_deg, msg);
    k_gemm<8, false><<<gemmGrid, 256, 0, stream>>>(h1, msg, frag1, b1, h2);
    // Layer 3
    k_agg<<<aggGrid, 256, 0, stream>>>(h2, offs, edge_src, inv_deg, msg);
    k_gemm<4, true><<<gemmGrid, 256, 0, stream>>>(h2, msg, frag2, b2, out);
}

// Round 11
// 324.452 us; speedup vs baseline: 1.3413x; 1.3413x over previous
//
#include <hip/hip_runtime.h>
#include <hip/hip_bf16.h>

#define N_NODES 50000
#define N_EDGES 800000
#define SCAN_B 256
#define SCAN_NB ((N_NODES + SCAN_B - 1) / SCAN_B)  // 196

typedef __attribute__((ext_vector_type(8))) short bf16x8;
typedef __attribute__((ext_vector_type(4))) float f32x4;

__device__ __forceinline__ float bf2f(unsigned short u) {
    unsigned int x = ((unsigned int)u) << 16;
    return __uint_as_float(x);
}
__device__ __forceinline__ unsigned short f2bf(float f) {
    unsigned int x = __float_as_uint(f);
    unsigned int lsb = (x >> 16) & 1u;
    x += 0x7fffu + lsb;
    return (unsigned short)(x >> 16);
}

// ---------------- prep: W fragments (3 layers) + features->bf16 + deg zeroing ----------------
// blocks [0,16): frag0; [16,32): frag1; [32,40): frag2; [40,40+NF2): f2bf; rest: zero deg.
// (R10 lesson: merging small independent launches is fine; merging TLP-hungry phases into
//  one co-resident cooperative kernel is not.)
#define NF2 ((N_NODES * 64 + 255) / 256)  // 12500 f2bf blocks (n2 = N*128/2)
__global__ __launch_bounds__(256) void k_prep(
        const float* __restrict__ Ws0, const float* __restrict__ Wn0,
        const float* __restrict__ Ws1, const float* __restrict__ Wn1,
        const float* __restrict__ Ws2, const float* __restrict__ Wn2,
        __hip_bfloat16* __restrict__ frag0, __hip_bfloat16* __restrict__ frag1,
        __hip_bfloat16* __restrict__ frag2,
        const float2* __restrict__ fin, unsigned int* __restrict__ fout,
        int* __restrict__ deg) {
    int b = blockIdx.x;
    if (b >= 40 + NF2) {  // zero deg
        int i = (b - 40 - NF2) * 256 + threadIdx.x;
        if (i < N_NODES) deg[i] = 0;
        return;
    }
    if (b >= 40) {  // features fp32 -> bf16 (packed pairs)
        int i = (b - 40) * 256 + threadIdx.x;
        if (i < N_NODES * 64) {
            float2 v = fin[i];
            fout[i] = ((unsigned int)f2bf(v.y) << 16) | (unsigned int)f2bf(v.x);
        }
        return;
    }
    const float* Wself;
    const float* Wneigh;
    __hip_bfloat16* frag;
    int Dout, lb;
    if (b < 16)      { Wself = Ws0; Wneigh = Wn0; frag = frag0; Dout = 128; lb = b; }
    else if (b < 32) { Wself = Ws1; Wneigh = Wn1; frag = frag1; Dout = 128; lb = b - 16; }
    else             { Wself = Ws2; Wneigh = Wn2; frag = frag2; Dout = 64;  lb = b - 32; }
    int t = lb * 256 + threadIdx.x;
    int nCt = Dout >> 4;
    int total = nCt * 8 * 64;
    if (t >= total) return;
    int lane = t & 63;
    int kt = (t >> 6) & 7;
    int ct = t >> 9;
    int q = lane >> 4;
    int n = ct * 16 + (lane & 15);
    unsigned short* dstp = (unsigned short*)frag + ((size_t)((ct * 8 + kt) * 64 + lane)) * 8;
    #pragma unroll
    for (int j = 0; j < 8; ++j) {
        int k = kt * 32 + q * 8 + j;
        float v = (k < 128) ? Wself[k * Dout + n] : Wneigh[(k - 128) * Dout + n];
        dstp[j] = f2bf(v);
    }
}

// ---------------- CSR build (R6/R8-proven separate-kernel chain) ----------------

__global__ void k_deg(const int* __restrict__ dst, int* __restrict__ deg) {
    int e = blockIdx.x * blockDim.x + threadIdx.x;
    if (e < N_EDGES) atomicAdd(&deg[dst[e]], 1);
}

__global__ __launch_bounds__(SCAN_B) void k_scan1(const int* __restrict__ deg,
                                                  int* __restrict__ blocksum) {
    int i = blockIdx.x * SCAN_B + threadIdx.x;
    int v = (i < N_NODES) ? deg[i] : 0;
    #pragma unroll
    for (int d = 1; d < 64; d <<= 1) v += __shfl_xor(v, d);
    __shared__ int ws[SCAN_B / 64];
    int wv = threadIdx.x >> 6, lane = threadIdx.x & 63;
    if (lane == 0) ws[wv] = v;
    __syncthreads();
    if (threadIdx.x == 0) blocksum[blockIdx.x] = ws[0] + ws[1] + ws[2] + ws[3];
}

__global__ __launch_bounds__(SCAN_B) void k_scan2(const int* __restrict__ blocksum,
                                                  int* __restrict__ blockoff,
                                                  int* __restrict__ offsets) {
    __shared__ int buf[SCAN_B];
    int tid = threadIdx.x;
    int v = (tid < SCAN_NB) ? blocksum[tid] : 0;
    buf[tid] = v;
    __syncthreads();
    for (int off = 1; off < SCAN_B; off <<= 1) {
        int t = (tid >= off) ? buf[tid - off] : 0;
        __syncthreads();
        buf[tid] += t;
        __syncthreads();
    }
    if (tid < SCAN_NB) blockoff[tid] = buf[tid] - v;  // exclusive
    if (tid == 0) offsets[N_NODES] = N_EDGES;         // total degree == E
}

__global__ __launch_bounds__(SCAN_B) void k_scan3(const int* __restrict__ deg,
                                                  const int* __restrict__ blockoff,
                                                  int* __restrict__ offsets,
                                                  int* __restrict__ pos,
                                                  float* __restrict__ inv_deg) {
    int tid = threadIdx.x;
    int i = blockIdx.x * SCAN_B + tid;
    int v = (i < N_NODES) ? deg[i] : 0;
    int lane = tid & 63, wv = tid >> 6;
    int s = v;
    #pragma unroll
    for (int d = 1; d < 64; d <<= 1) {
        int t = __shfl_up(s, d);
        if (lane >= d) s += t;
    }
    __shared__ int wsum[SCAN_B / 64];
    if (lane == 63) wsum[wv] = s;
    __syncthreads();
    int add = 0;
    #pragma unroll
    for (int w = 0; w < SCAN_B / 64; ++w)
        if (w < wv) add += wsum[w];
    int excl = blockoff[blockIdx.x] + s + add - v;
    if (i < N_NODES) {
        offsets[i] = excl;
        pos[i] = excl;
        inv_deg[i] = 1.0f / (float)max(v, 1);
    }
}

__global__ void k_scatter(const int* __restrict__ src, const int* __restrict__ dst,
                          int* __restrict__ pos, int* __restrict__ edge_src) {
    int e = blockIdx.x * blockDim.x + threadIdx.x;
    if (e < N_EDGES) {
        int p = atomicAdd(&pos[dst[e]], 1);
        edge_src[p] = src[e];
    }
}

// ---------------- mean aggregation (one wave per node, half-wave edge pairs) ----------------
// h: [N,128] bf16. half=lane>>5 picks edge parity, sub=lane&31 owns cols [4*sub..4*sub+3]
// via one dwordx2. 16 edges/iter, 8 independent 8B gathers in flight per lane.
// At the scattered-gather pipe ceiling (~2.3 TB/s) — deeper MLP neutral (R8).
__global__ void k_agg(const __hip_bfloat16* __restrict__ hv, const int* __restrict__ offsets,
                      const int* __restrict__ edge_src, const float* __restrict__ inv_deg,
                      __hip_bfloat16* __restrict__ msg) {
    int gid = blockIdx.x * blockDim.x + threadIdx.x;
    int node = gid >> 6;
    int lane = gid & 63;
    if (node >= N_NODES) return;
    int half = lane >> 5;
    int sub = lane & 31;
    int beg = offsets[node], end = offsets[node + 1];
    const uint2* hp = (const uint2*)hv;  // 32 uint2 per row

    float acc[4][4];
    #pragma unroll
    for (int g = 0; g < 4; ++g)
        #pragma unroll
        for (int c = 0; c < 4; ++c) acc[g][c] = 0.f;

    int i = beg;
    for (; i + 16 <= end; i += 16) {
        int s0 = edge_src[i + half];
        int s1 = edge_src[i + 2 + half];
        int s2 = edge_src[i + 4 + half];
        int s3 = edge_src[i + 6 + half];
        int s4 = edge_src[i + 8 + half];
        int s5 = edge_src[i + 10 + half];
        int s6 = edge_src[i + 12 + half];
        int s7 = edge_src[i + 14 + half];
        uint2 u0 = hp[(size_t)s0 * 32 + sub];
        uint2 u1 = hp[(size_t)s1 * 32 + sub];
        uint2 u2 = hp[(size_t)s2 * 32 + sub];
        uint2 u3 = hp[(size_t)s3 * 32 + sub];
        uint2 u4 = hp[(size_t)s4 * 32 + sub];
        uint2 u5 = hp[(size_t)s5 * 32 + sub];
        uint2 u6 = hp[(size_t)s6 * 32 + sub];
        uint2 u7 = hp[(size_t)s7 * 32 + sub];
        acc[0][0] += bf2f((unsigned short)(u0.x & 0xffffu)); acc[0][1] += bf2f((unsigned short)(u0.x >> 16));
        acc[0][2] += bf2f((unsigned short)(u0.y & 0xffffu)); acc[0][3] += bf2f((unsigned short)(u0.y >> 16));
        acc[1][0] += bf2f((unsigned short)(u1.x & 0xffffu)); acc[1][1] += bf2f((unsigned short)(u1.x >> 16));
        acc[1][2] += bf2f((unsigned short)(u1.y & 0xffffu)); acc[1][3] += bf2f((unsigned short)(u1.y >> 16));
        acc[2][0] += bf2f((unsigned short)(u2.x & 0xffffu)); acc[2][1] += bf2f((unsigned short)(u2.x >> 16));
        acc[2][2] += bf2f((unsigned short)(u2.y & 0xffffu)); acc[2][3] += bf2f((unsigned short)(u2.y >> 16));
        acc[3][0] += bf2f((unsigned short)(u3.x & 0xffffu)); acc[3][1] += bf2f((unsigned short)(u3.x >> 16));
        acc[3][2] += bf2f((unsigned short)(u3.y & 0xffffu)); acc[3][3] += bf2f((unsigned short)(u3.y >> 16));
        acc[0][0] += bf2f((unsigned short)(u4.x & 0xffffu)); acc[0][1] += bf2f((unsigned short)(u4.x >> 16));
        acc[0][2] += bf2f((unsigned short)(u4.y & 0xffffu)); acc[0][3] += bf2f((unsigned short)(u4.y >> 16));
        acc[1][0] += bf2f((unsigned short)(u5.x & 0xffffu)); acc[1][1] += bf2f((unsigned short)(u5.x >> 16));
        acc[1][2] += bf2f((unsigned short)(u5.y & 0xffffu)); acc[1][3] += bf2f((unsigned short)(u5.y >> 16));
        acc[2][0] += bf2f((unsigned short)(u6.x & 0xffffu)); acc[2][1] += bf2f((unsigned short)(u6.x >> 16));
        acc[2][2] += bf2f((unsigned short)(u6.y & 0xffffu)); acc[2][3] += bf2f((unsigned short)(u6.y >> 16));
        acc[3][0] += bf2f((unsigned short)(u7.x & 0xffffu)); acc[3][1] += bf2f((unsigned short)(u7.x >> 16));
        acc[3][2] += bf2f((unsigned short)(u7.y & 0xffffu)); acc[3][3] += bf2f((unsigned short)(u7.y >> 16));
    }
    for (; i + 8 <= end; i += 8) {
        int s0 = edge_src[i + half];
        int s1 = edge_src[i + 2 + half];
        int s2 = edge_src[i + 4 + half];
        int s3 = edge_src[i + 6 + half];
        uint2 u0 = hp[(size_t)s0 * 32 + sub];
        uint2 u1 = hp[(size_t)s1 * 32 + sub];
        uint2 u2 = hp[(size_t)s2 * 32 + sub];
        uint2 u3 = hp[(size_t)s3 * 32 + sub];
        acc[0][0] += bf2f((unsigned short)(u0.x & 0xffffu)); acc[0][1] += bf2f((unsigned short)(u0.x >> 16));
        acc[0][2] += bf2f((unsigned short)(u0.y & 0xffffu)); acc[0][3] += bf2f((unsigned short)(u0.y >> 16));
        acc[1][0] += bf2f((unsigned short)(u1.x & 0xffffu)); acc[1][1] += bf2f((unsigned short)(u1.x >> 16));
        acc[1][2] += bf2f((unsigned short)(u1.y & 0xffffu)); acc[1][3] += bf2f((unsigned short)(u1.y >> 16));
        acc[2][0] += bf2f((unsigned short)(u2.x & 0xffffu)); acc[2][1] += bf2f((unsigned short)(u2.x >> 16));
        acc[2][2] += bf2f((unsigned short)(u2.y & 0xffffu)); acc[2][3] += bf2f((unsigned short)(u2.y >> 16));
        acc[3][0] += bf2f((unsigned short)(u3.x & 0xffffu)); acc[3][1] += bf2f((unsigned short)(u3.x >> 16));
        acc[3][2] += bf2f((unsigned short)(u3.y & 0xffffu)); acc[3][3] += bf2f((unsigned short)(u3.y >> 16));
    }
    for (; i + 4 <= end; i += 4) {
        int s0 = edge_src[i + half];
        int s1 = edge_src[i + 2 + half];
        uint2 u0 = hp[(size_t)s0 * 32 + sub];
        uint2 u1 = hp[(size_t)s1 * 32 + sub];
        acc[0][0] += bf2f((unsigned short)(u0.x & 0xffffu)); acc[0][1] += bf2f((unsigned short)(u0.x >> 16));
        acc[0][2] += bf2f((unsigned short)(u0.y & 0xffffu)); acc[0][3] += bf2f((unsigned short)(u0.y >> 16));
        acc[1][0] += bf2f((unsigned short)(u1.x & 0xffffu)); acc[1][1] += bf2f((unsigned short)(u1.x >> 16));
        acc[1][2] += bf2f((unsigned short)(u1.y & 0xffffu)); acc[1][3] += bf2f((unsigned short)(u1.y >> 16));
    }
    for (; i + 2 <= end; i += 2) {
        int s0 = edge_src[i + half];
        uint2 u0 = hp[(size_t)s0 * 32 + sub];
        acc[0][0] += bf2f((unsigned short)(u0.x & 0xffffu)); acc[0][1] += bf2f((unsigned short)(u0.x >> 16));
        acc[0][2] += bf2f((unsigned short)(u0.y & 0xffffu)); acc[0][3] += bf2f((unsigned short)(u0.y >> 16));
    }
    if (i < end && half == 0) {  // odd leftover: half 0 only
        int s0 = edge_src[i];
        uint2 u0 = hp[(size_t)s0 * 32 + sub];
        acc[0][0] += bf2f((unsigned short)(u0.x & 0xffffu)); acc[0][1] += bf2f((unsigned short)(u0.x >> 16));
        acc[0][2] += bf2f((unsigned short)(u0.y & 0xffffu)); acc[0][3] += bf2f((unsigned short)(u0.y >> 16));
    }

    float r0 = acc[0][0] + acc[1][0] + acc[2][0] + acc[3][0];
    float r1 = acc[0][1] + acc[1][1] + acc[2][1] + acc[3][1];
    float r2 = acc[0][2] + acc[1][2] + acc[2][2] + acc[3][2];
    float r3 = acc[0][3] + acc[1][3] + acc[2][3] + acc[3][3];
    r0 += __shfl_xor(r0, 32);
    r1 += __shfl_xor(r1, 32);
    r2 += __shfl_xor(r2, 32);
    r3 += __shfl_xor(r3, 32);
    if (half == 0) {
        float w = inv_deg[node];
        uint2 o;
        o.x = ((unsigned int)f2bf(r1 * w) << 16) | (unsigned int)f2bf(r0 * w);
        o.y = ((unsigned int)f2bf(r3 * w) << 16) | (unsigned int)f2bf(r2 * w);
        ((uint2*)msg)[(size_t)node * 32 + sub] = o;
    }
}

// ---------------- fused GEMM + bias (+ relu + l2norm) ----------------
template <int NCT, bool LAST>
__global__ __launch_bounds__(256) void k_gemm(const __hip_bfloat16* __restrict__ Aself,
                                              const __hip_bfloat16* __restrict__ Aneigh,
                                              const __hip_bfloat16* __restrict__ frag,
                                              const float* __restrict__ bias,
                                              void* __restrict__ out_) {
    constexpr int Dout = NCT * 16;
    int tid = threadIdx.x;
    int wv = tid >> 6, lane = tid & 63;
    int n0 = blockIdx.x * 64 + wv * 16;
    if (n0 >= N_NODES) return;  // wave-uniform early exit, no LDS used
    int q = lane >> 4, l15 = lane & 15;
    int rowA = n0 + l15;
    if (rowA > N_NODES - 1) rowA = N_NODES - 1;  // clamp loads; stores guarded below

    f32x4 acc[NCT];
    #pragma unroll
    for (int c = 0; c < NCT; ++c) acc[c] = (f32x4){0.f, 0.f, 0.f, 0.f};

    const bf16x8* fragv = (const bf16x8*)frag;
    #pragma unroll
    for (int kt = 0; kt < 8; ++kt) {
        int kb = (kt & 3) * 32 + q * 8;
        const __hip_bfloat16* Ab = (kt < 4) ? Aself : Aneigh;
        bf16x8 a = *(const bf16x8*)(Ab + (size_t)rowA * 128 + kb);
        #pragma unroll
        for (int ct = 0; ct < NCT; ++ct) {
            bf16x8 b = fragv[(ct * 8 + kt) * 64 + lane];
            acc[ct] = __builtin_amdgcn_mfma_f32_16x16x32_bf16(a, b, acc[ct], 0, 0, 0);
        }
    }

    float ss[4] = {0.f, 0.f, 0.f, 0.f};
    #pragma unroll
    for (int ct = 0; ct < NCT; ++ct) {
        float bc = bias[ct * 16 + l15];
        #pragma unroll
        for (int r = 0; r < 4; ++r) {
            float v = acc[ct][r] + bc;
            if (!LAST) v = fmaxf(v, 0.0f);
            acc[ct][r] = v;
            ss[r] += v * v;
        }
    }

    float scale[4];
    #pragma unroll
    for (int r = 0; r < 4; ++r) {
        if (!LAST) {
            float s = ss[r];
            s += __shfl_xor(s, 1);
            s += __shfl_xor(s, 2);
            s += __shfl_xor(s, 4);
            s += __shfl_xor(s, 8);
            scale[r] = 1.0f / fmaxf(sqrtf(s), 1e-12f);
        } else {
            scale[r] = 1.0f;
        }
    }

    #pragma unroll
    for (int ct = 0; ct < NCT; ++ct) {
        #pragma unroll
        for (int r = 0; r < 4; ++r) {
            int row = n0 + q * 4 + r;
            if (row < N_NODES) {
                float v = acc[ct][r] * scale[r];
                if (LAST)
                    ((float*)out_)[(size_t)row * Dout + ct * 16 + l15] = v;
                else
                    ((unsigned short*)out_)[(size_t)row * Dout + ct * 16 + l15] = f2bf(v);
            }
        }
    }
}

// ---------------- host launch ----------------

extern "C" void kernel_launch(void* const* d_in, const int* in_sizes, int n_in,
                              void* d_out, int out_size, void* d_ws, size_t ws_size,
                              hipStream_t stream) {
    const float* features = (const float*)d_in[0];
    const int* src = (const int*)d_in[1];
    const int* dst = (const int*)d_in[2];
    const float* Ws0 = (const float*)d_in[3];
    const float* Wn0 = (const float*)d_in[4];
    const float* b0  = (const float*)d_in[5];
    const float* Ws1 = (const float*)d_in[6];
    const float* Wn1 = (const float*)d_in[7];
    const float* b1  = (const float*)d_in[8];
    const float* Ws2 = (const float*)d_in[9];
    const float* Wn2 = (const float*)d_in[10];
    const float* b2  = (const float*)d_in[11];
    float* out = (float*)d_out;

    char* ws = (char*)d_ws;
    size_t off = 0;
    auto alloc = [&](size_t bytes) -> void* {
        void* p = ws + off;
        off = (off + bytes + 255) & ~(size_t)255;
        return p;
    };
    int*   deg      = (int*)alloc((size_t)N_NODES * 4);
    int*   pos      = (int*)alloc((size_t)N_NODES * 4);
    int*   offs     = (int*)alloc((size_t)(N_NODES + 1) * 4);
    int*   edge_src = (int*)alloc((size_t)N_EDGES * 4);
    float* inv_deg  = (float*)alloc((size_t)N_NODES * 4);
    int*   blocksum = (int*)alloc((size_t)SCAN_NB * 4);
    int*   blockoff = (int*)alloc((size_t)SCAN_NB * 4);
    __hip_bfloat16* fbf = (__hip_bfloat16*)alloc((size_t)N_NODES * 128 * 2);
    __hip_bfloat16* msg = (__hip_bfloat16*)alloc((size_t)N_NODES * 128 * 2);
    __hip_bfloat16* h1  = (__hip_bfloat16*)alloc((size_t)N_NODES * 128 * 2);
    __hip_bfloat16* h2  = (__hip_bfloat16*)alloc((size_t)N_NODES * 128 * 2);
    __hip_bfloat16* frag0 = (__hip_bfloat16*)alloc((size_t)8 * 8 * 64 * 8 * 2);
    __hip_bfloat16* frag1 = (__hip_bfloat16*)alloc((size_t)8 * 8 * 64 * 8 * 2);
    __hip_bfloat16* frag2 = (__hip_bfloat16*)alloc((size_t)4 * 8 * 64 * 8 * 2);

    // prep (W frags + f2bf + deg zero), then CSR chain (R6/R8-proven)
    const int prepGrid = 40 + NF2 + SCAN_NB;
    k_prep<<<prepGrid, 256, 0, stream>>>(Ws0, Wn0, Ws1, Wn1, Ws2, Wn2,
                                         frag0, frag1, frag2,
                                         (const float2*)features, (unsigned int*)fbf, deg);
    k_deg<<<(N_EDGES + 255) / 256, 256, 0, stream>>>(dst, deg);
    k_scan1<<<SCAN_NB, SCAN_B, 0, stream>>>(deg, blocksum);
    k_scan2<<<1, SCAN_B, 0, stream>>>(blocksum, blockoff, offs);
    k_scan3<<<SCAN_NB, SCAN_B, 0, stream>>>(deg, blockoff, offs, pos, inv_deg);
    k_scatter<<<(N_EDGES + 255) / 256, 256, 0, stream>>>(src, dst, pos, edge_src);

    const int aggGrid = (N_NODES * 64) / 256;  // 12500
    const int gemmGrid = (N_NODES + 63) / 64;  // 782

    // Layer 1
    k_agg<<<aggGrid, 256, 0, stream>>>(fbf, offs, edge_src, inv_deg, msg);
    k_gemm<8, false><<<gemmGrid, 256, 0, stream>>>(fbf, msg, frag0, b0, h1);
    // Layer 2
    k_agg<<<aggGrid, 256, 0, stream>>>(h1, offs, edge_src, inv_deg, msg);
    k_gemm<8, false><<<gemmGrid, 256, 0, stream>>>(h1, msg, frag1, b1, h2);
    // Layer 3
    k_agg<<<aggGrid, 256, 0, stream>>>(h2, offs, edge_src, inv_deg, msg);
    k_gemm<4, true><<<gemmGrid, 256, 0, stream>>>(h2, msg, frag2, b2, out);
}

// Round 12
// 267.745 us; speedup vs baseline: 1.6253x; 1.2118x over previous
//
#include <hip/hip_runtime.h>
#include <hip/hip_bf16.h>

#define N_NODES 50000
#define N_EDGES 800000
#define NBUCKET 196        // NPB=256: bucket = dst>>8, local = dst&255
#define NPB 256
#define BUCKET_CAP 7168    // padded occupancy ~6470 mean (196 blk * pad16(~21)); 10+ sigma margin
#define PART_EDGES 4096
#define PART_BLOCKS ((N_EDGES + PART_EDGES - 1) / PART_EDGES)  // 196
#define SENTINEL 0xFFFFFFFFu

typedef __attribute__((ext_vector_type(8))) short bf16x8;
typedef __attribute__((ext_vector_type(4))) float f32x4;

__device__ __forceinline__ float bf2f(unsigned short u) {
    unsigned int x = ((unsigned int)u) << 16;
    return __uint_as_float(x);
}
__device__ __forceinline__ unsigned short f2bf(float f) {
    unsigned int x = __float_as_uint(f);
    unsigned int lsb = (x >> 16) & 1u;
    x += 0x7fffu + lsb;
    return (unsigned short)(x >> 16);
}

// ---------------- prep: W fragments + features->bf16 + zero cursor/valid ----------------
#define NF2 ((N_NODES * 64 + 255) / 256)  // 12500 f2bf blocks
__global__ __launch_bounds__(256) void k_prep(
        const float* __restrict__ Ws0, const float* __restrict__ Wn0,
        const float* __restrict__ Ws1, const float* __restrict__ Wn1,
        const float* __restrict__ Ws2, const float* __restrict__ Wn2,
        __hip_bfloat16* __restrict__ frag0, __hip_bfloat16* __restrict__ frag1,
        __hip_bfloat16* __restrict__ frag2,
        const float2* __restrict__ fin, unsigned int* __restrict__ fout,
        int* __restrict__ cursor, int* __restrict__ valid) {
    int b = blockIdx.x;
    if (b >= 40 + NF2) {  // zero the bucket counters
        int tid = threadIdx.x;
        if (tid < NBUCKET) { cursor[tid] = 0; valid[tid] = 0; }
        return;
    }
    if (b >= 40) {  // features fp32 -> bf16 (packed pairs)
        int i = (b - 40) * 256 + threadIdx.x;
        if (i < N_NODES * 64) {
            float2 v = fin[i];
            fout[i] = ((unsigned int)f2bf(v.y) << 16) | (unsigned int)f2bf(v.x);
        }
        return;
    }
    const float* Wself;
    const float* Wneigh;
    __hip_bfloat16* frag;
    int Dout, lb;
    if (b < 16)      { Wself = Ws0; Wneigh = Wn0; frag = frag0; Dout = 128; lb = b; }
    else if (b < 32) { Wself = Ws1; Wneigh = Wn1; frag = frag1; Dout = 128; lb = b - 16; }
    else             { Wself = Ws2; Wneigh = Wn2; frag = frag2; Dout = 64;  lb = b - 32; }
    int t = lb * 256 + threadIdx.x;
    int nCt = Dout >> 4;
    int total = nCt * 8 * 64;
    if (t >= total) return;
    int lane = t & 63;
    int kt = (t >> 6) & 7;
    int ct = t >> 9;
    int q = lane >> 4;
    int n = ct * 16 + (lane & 15);
    unsigned short* dstp = (unsigned short*)frag + ((size_t)((ct * 8 + kt) * 64 + lane)) * 8;
    #pragma unroll
    for (int j = 0; j < 8; ++j) {
        int k = kt * 32 + q * 8 + j;
        float v = (k < 128) ? Wself[k * Dout + n] : Wneigh[(k - 128) * Dout + n];
        dstp[j] = f2bf(v);
    }
}

// ---------------- bucketed CSR build v2: all cross-block write runs 64B-aligned ----------------
// Phase A: per-block histogram over 196 buckets; reservations padded to 16 ints (64B) and
// sentinel-filled by the OWNING block -> no two blocks ever dirty the same line of bucketArr.
__global__ __launch_bounds__(256) void k_partA(const int* __restrict__ src,
                                               const int* __restrict__ dst,
                                               int* __restrict__ cursor,
                                               int* __restrict__ valid,
                                               unsigned int* __restrict__ bucketArr) {
    __shared__ int hist[NBUCKET];
    __shared__ int base[NBUCKET];
    __shared__ int cnt[NBUCKET];
    int tid = threadIdx.x;
    if (tid < NBUCKET) hist[tid] = 0;
    __syncthreads();
    int e0 = blockIdx.x * PART_EDGES;
    for (int j = 0; j < PART_EDGES; j += 256) {
        int e = e0 + j + tid;
        if (e < N_EDGES) atomicAdd(&hist[dst[e] >> 8], 1);
    }
    __syncthreads();
    if (tid < NBUCKET) {
        int h = hist[tid];
        int hp = (h + 15) & ~15;  // 64B-aligned reservation
        int b0 = atomicAdd(&cursor[tid], hp);
        atomicAdd(&valid[tid], h);
        base[tid] = b0;
        cnt[tid] = 0;
        for (int k = h; k < hp; ++k) {  // sentinel-fill our own padding slots
            int p = b0 + k;
            if (p < BUCKET_CAP) bucketArr[(size_t)tid * BUCKET_CAP + p] = SENTINEL;
        }
    }
    __syncthreads();
    for (int j = 0; j < PART_EDGES; j += 256) {
        int e = e0 + j + tid;
        if (e < N_EDGES) {
            int d = dst[e];
            int b = d >> 8;
            int p = base[b] + atomicAdd(&cnt[b], 1);
            if (p < BUCKET_CAP)
                bucketArr[(size_t)b * BUCKET_CAP + p] =
                    (unsigned int)src[e] | ((unsigned int)(d & 255) << 16);
        }
    }
}

// scan pad16(valid[b]) -> 64B-aligned global base per bucket
__global__ __launch_bounds__(256) void k_scanB(const int* __restrict__ valid,
                                               int* __restrict__ gbase) {
    __shared__ int buf[256];
    int tid = threadIdx.x;
    int v = (tid < NBUCKET) ? valid[tid] : 0;
    int pv = (v + 15) & ~15;
    buf[tid] = pv;
    __syncthreads();
    for (int off = 1; off < 256; off <<= 1) {
        int t = (tid >= off) ? buf[tid - off] : 0;
        __syncthreads();
        buf[tid] += t;
        __syncthreads();
    }
    if (tid < NBUCKET) gbase[tid] = buf[tid] - pv;
}

// Phase B: one block per bucket; LDS-local CSR; coalesced aligned writes of
// off_beg/off_end/inv_deg (runs at b*256) and edge_src (runs at 16-aligned gbase).
__global__ __launch_bounds__(256) void k_partB(const unsigned int* __restrict__ bucketArr,
                                               const int* __restrict__ cursor,
                                               const int* __restrict__ gbase,
                                               int* __restrict__ off_beg,
                                               int* __restrict__ off_end,
                                               float* __restrict__ inv_deg,
                                               int* __restrict__ edge_src) {
    __shared__ unsigned int ed[BUCKET_CAP];
    __shared__ int csr[BUCKET_CAP];
    __shared__ int hist[256];
    __shared__ int lbase[256];
    __shared__ int lcnt[256];
    __shared__ int tot_s;
    int b = blockIdx.x;
    int tid = threadIdx.x;
    int size = min(cursor[b], BUCKET_CAP);
    int gb = gbase[b];
    int nbase = b * NPB;
    int ncount = min(NPB, N_NODES - nbase);
    hist[tid] = 0;
    __syncthreads();
    for (int j = 0; j < BUCKET_CAP; j += 256) {
        int i = j + tid;
        if (i < size) {
            unsigned int u = bucketArr[(size_t)b * BUCKET_CAP + i];
            ed[i] = u;
            if ((u >> 16) < 256u) atomicAdd(&hist[u >> 16], 1);  // skip sentinels
        }
    }
    __syncthreads();
    int v = hist[tid];
    lbase[tid] = v;
    __syncthreads();
    for (int off = 1; off < 256; off <<= 1) {
        int t = (tid >= off) ? lbase[tid - off] : 0;
        __syncthreads();
        lbase[tid] += t;
        __syncthreads();
    }
    int excl = lbase[tid] - v;
    if (tid == 255) tot_s = lbase[255];
    __syncthreads();
    lbase[tid] = excl;
    lcnt[tid] = 0;
    if (tid < ncount) {
        off_beg[nbase + tid] = gb + excl;
        off_end[nbase + tid] = gb + excl + v;
        inv_deg[nbase + tid] = 1.0f / (float)max(v, 1);
    }
    __syncthreads();
    for (int j = 0; j < BUCKET_CAP; j += 256) {
        int i = j + tid;
        if (i < size) {
            unsigned int u = ed[i];
            unsigned int ld = u >> 16;
            if (ld < 256u) {
                int p = lbase[ld] + atomicAdd(&lcnt[ld], 1);
                csr[p] = (int)(u & 0xffffu);
            }
        }
    }
    __syncthreads();
    int tot = tot_s;
    for (int j = 0; j < BUCKET_CAP; j += 256) {
        int i = j + tid;
        if (i < tot) edge_src[gb + i] = csr[i];
    }
}

// ---------------- mean aggregation (one wave per node, half-wave edge pairs) ----------------
// 16 edges/iter, 8 independent 8B gathers in flight per lane; beg/end from off_beg/off_end.
__global__ void k_agg(const __hip_bfloat16* __restrict__ hv,
                      const int* __restrict__ off_beg, const int* __restrict__ off_end,
                      const int* __restrict__ edge_src, const float* __restrict__ inv_deg,
                      __hip_bfloat16* __restrict__ msg) {
    int gid = blockIdx.x * blockDim.x + threadIdx.x;
    int node = gid >> 6;
    int lane = gid & 63;
    if (node >= N_NODES) return;
    int half = lane >> 5;
    int sub = lane & 31;
    int beg = off_beg[node], end = off_end[node];
    const uint2* hp = (const uint2*)hv;  // 32 uint2 per row

    float acc[4][4];
    #pragma unroll
    for (int g = 0; g < 4; ++g)
        #pragma unroll
        for (int c = 0; c < 4; ++c) acc[g][c] = 0.f;

    int i = beg;
    for (; i + 16 <= end; i += 16) {
        int s0 = edge_src[i + half];
        int s1 = edge_src[i + 2 + half];
        int s2 = edge_src[i + 4 + half];
        int s3 = edge_src[i + 6 + half];
        int s4 = edge_src[i + 8 + half];
        int s5 = edge_src[i + 10 + half];
        int s6 = edge_src[i + 12 + half];
        int s7 = edge_src[i + 14 + half];
        uint2 u0 = hp[(size_t)s0 * 32 + sub];
        uint2 u1 = hp[(size_t)s1 * 32 + sub];
        uint2 u2 = hp[(size_t)s2 * 32 + sub];
        uint2 u3 = hp[(size_t)s3 * 32 + sub];
        uint2 u4 = hp[(size_t)s4 * 32 + sub];
        uint2 u5 = hp[(size_t)s5 * 32 + sub];
        uint2 u6 = hp[(size_t)s6 * 32 + sub];
        uint2 u7 = hp[(size_t)s7 * 32 + sub];
        acc[0][0] += bf2f((unsigned short)(u0.x & 0xffffu)); acc[0][1] += bf2f((unsigned short)(u0.x >> 16));
        acc[0][2] += bf2f((unsigned short)(u0.y & 0xffffu)); acc[0][3] += bf2f((unsigned short)(u0.y >> 16));
        acc[1][0] += bf2f((unsigned short)(u1.x & 0xffffu)); acc[1][1] += bf2f((unsigned short)(u1.x >> 16));
        acc[1][2] += bf2f((unsigned short)(u1.y & 0xffffu)); acc[1][3] += bf2f((unsigned short)(u1.y >> 16));
        acc[2][0] += bf2f((unsigned short)(u2.x & 0xffffu)); acc[2][1] += bf2f((unsigned short)(u2.x >> 16));
        acc[2][2] += bf2f((unsigned short)(u2.y & 0xffffu)); acc[2][3] += bf2f((unsigned short)(u2.y >> 16));
        acc[3][0] += bf2f((unsigned short)(u3.x & 0xffffu)); acc[3][1] += bf2f((unsigned short)(u3.x >> 16));
        acc[3][2] += bf2f((unsigned short)(u3.y & 0xffffu)); acc[3][3] += bf2f((unsigned short)(u3.y >> 16));
        acc[0][0] += bf2f((unsigned short)(u4.x & 0xffffu)); acc[0][1] += bf2f((unsigned short)(u4.x >> 16));
        acc[0][2] += bf2f((unsigned short)(u4.y & 0xffffu)); acc[0][3] += bf2f((unsigned short)(u4.y >> 16));
        acc[1][0] += bf2f((unsigned short)(u5.x & 0xffffu)); acc[1][1] += bf2f((unsigned short)(u5.x >> 16));
        acc[1][2] += bf2f((unsigned short)(u5.y & 0xffffu)); acc[1][3] += bf2f((unsigned short)(u5.y >> 16));
        acc[2][0] += bf2f((unsigned short)(u6.x & 0xffffu)); acc[2][1] += bf2f((unsigned short)(u6.x >> 16));
        acc[2][2] += bf2f((unsigned short)(u6.y & 0xffffu)); acc[2][3] += bf2f((unsigned short)(u6.y >> 16));
        acc[3][0] += bf2f((unsigned short)(u7.x & 0xffffu)); acc[3][1] += bf2f((unsigned short)(u7.x >> 16));
        acc[3][2] += bf2f((unsigned short)(u7.y & 0xffffu)); acc[3][3] += bf2f((unsigned short)(u7.y >> 16));
    }
    for (; i + 8 <= end; i += 8) {
        int s0 = edge_src[i + half];
        int s1 = edge_src[i + 2 + half];
        int s2 = edge_src[i + 4 + half];
        int s3 = edge_src[i + 6 + half];
        uint2 u0 = hp[(size_t)s0 * 32 + sub];
        uint2 u1 = hp[(size_t)s1 * 32 + sub];
        uint2 u2 = hp[(size_t)s2 * 32 + sub];
        uint2 u3 = hp[(size_t)s3 * 32 + sub];
        acc[0][0] += bf2f((unsigned short)(u0.x & 0xffffu)); acc[0][1] += bf2f((unsigned short)(u0.x >> 16));
        acc[0][2] += bf2f((unsigned short)(u0.y & 0xffffu)); acc[0][3] += bf2f((unsigned short)(u0.y >> 16));
        acc[1][0] += bf2f((unsigned short)(u1.x & 0xffffu)); acc[1][1] += bf2f((unsigned short)(u1.x >> 16));
        acc[1][2] += bf2f((unsigned short)(u1.y & 0xffffu)); acc[1][3] += bf2f((unsigned short)(u1.y >> 16));
        acc[2][0] += bf2f((unsigned short)(u2.x & 0xffffu)); acc[2][1] += bf2f((unsigned short)(u2.x >> 16));
        acc[2][2] += bf2f((unsigned short)(u2.y & 0xffffu)); acc[2][3] += bf2f((unsigned short)(u2.y >> 16));
        acc[3][0] += bf2f((unsigned short)(u3.x & 0xffffu)); acc[3][1] += bf2f((unsigned short)(u3.x >> 16));
        acc[3][2] += bf2f((unsigned short)(u3.y & 0xffffu)); acc[3][3] += bf2f((unsigned short)(u3.y >> 16));
    }
    for (; i + 4 <= end; i += 4) {
        int s0 = edge_src[i + half];
        int s1 = edge_src[i + 2 + half];
        uint2 u0 = hp[(size_t)s0 * 32 + sub];
        uint2 u1 = hp[(size_t)s1 * 32 + sub];
        acc[0][0] += bf2f((unsigned short)(u0.x & 0xffffu)); acc[0][1] += bf2f((unsigned short)(u0.x >> 16));
        acc[0][2] += bf2f((unsigned short)(u0.y & 0xffffu)); acc[0][3] += bf2f((unsigned short)(u0.y >> 16));
        acc[1][0] += bf2f((unsigned short)(u1.x & 0xffffu)); acc[1][1] += bf2f((unsigned short)(u1.x >> 16));
        acc[1][2] += bf2f((unsigned short)(u1.y & 0xffffu)); acc[1][3] += bf2f((unsigned short)(u1.y >> 16));
    }
    for (; i + 2 <= end; i += 2) {
        int s0 = edge_src[i + half];
        uint2 u0 = hp[(size_t)s0 * 32 + sub];
        acc[0][0] += bf2f((unsigned short)(u0.x & 0xffffu)); acc[0][1] += bf2f((unsigned short)(u0.x >> 16));
        acc[0][2] += bf2f((unsigned short)(u0.y & 0xffffu)); acc[0][3] += bf2f((unsigned short)(u0.y >> 16));
    }
    if (i < end && half == 0) {
        int s0 = edge_src[i];
        uint2 u0 = hp[(size_t)s0 * 32 + sub];
        acc[0][0] += bf2f((unsigned short)(u0.x & 0xffffu)); acc[0][1] += bf2f((unsigned short)(u0.x >> 16));
        acc[0][2] += bf2f((unsigned short)(u0.y & 0xffffu)); acc[0][3] += bf2f((unsigned short)(u0.y >> 16));
    }

    float r0 = acc[0][0] + acc[1][0] + acc[2][0] + acc[3][0];
    float r1 = acc[0][1] + acc[1][1] + acc[2][1] + acc[3][1];
    float r2 = acc[0][2] + acc[1][2] + acc[2][2] + acc[3][2];
    float r3 = acc[0][3] + acc[1][3] + acc[2][3] + acc[3][3];
    r0 += __shfl_xor(r0, 32);
    r1 += __shfl_xor(r1, 32);
    r2 += __shfl_xor(r2, 32);
    r3 += __shfl_xor(r3, 32);
    if (half == 0) {
        float w = inv_deg[node];
        uint2 o;
        o.x = ((unsigned int)f2bf(r1 * w) << 16) | (unsigned int)f2bf(r0 * w);
        o.y = ((unsigned int)f2bf(r3 * w) << 16) | (unsigned int)f2bf(r2 * w);
        ((uint2*)msg)[(size_t)node * 32 + sub] = o;
    }
}

// ---------------- fused GEMM + bias (+ relu + l2norm) ----------------
template <int NCT, bool LAST>
__global__ __launch_bounds__(256) void k_gemm(const __hip_bfloat16* __restrict__ Aself,
                                              const __hip_bfloat16* __restrict__ Aneigh,
                                              const __hip_bfloat16* __restrict__ frag,
                                              const float* __restrict__ bias,
                                              void* __restrict__ out_) {
    constexpr int Dout = NCT * 16;
    int tid = threadIdx.x;
    int wv = tid >> 6, lane = tid & 63;
    int n0 = blockIdx.x * 64 + wv * 16;
    if (n0 >= N_NODES) return;
    int q = lane >> 4, l15 = lane & 15;
    int rowA = n0 + l15;
    if (rowA > N_NODES - 1) rowA = N_NODES - 1;

    f32x4 acc[NCT];
    #pragma unroll
    for (int c = 0; c < NCT; ++c) acc[c] = (f32x4){0.f, 0.f, 0.f, 0.f};

    const bf16x8* fragv = (const bf16x8*)frag;
    #pragma unroll
    for (int kt = 0; kt < 8; ++kt) {
        int kb = (kt & 3) * 32 + q * 8;
        const __hip_bfloat16* Ab = (kt < 4) ? Aself : Aneigh;
        bf16x8 a = *(const bf16x8*)(Ab + (size_t)rowA * 128 + kb);
        #pragma unroll
        for (int ct = 0; ct < NCT; ++ct) {
            bf16x8 b = fragv[(ct * 8 + kt) * 64 + lane];
            acc[ct] = __builtin_amdgcn_mfma_f32_16x16x32_bf16(a, b, acc[ct], 0, 0, 0);
        }
    }

    float ss[4] = {0.f, 0.f, 0.f, 0.f};
    #pragma unroll
    for (int ct = 0; ct < NCT; ++ct) {
        float bc = bias[ct * 16 + l15];
        #pragma unroll
        for (int r = 0; r < 4; ++r) {
            float v = acc[ct][r] + bc;
            if (!LAST) v = fmaxf(v, 0.0f);
            acc[ct][r] = v;
            ss[r] += v * v;
        }
    }

    float scale[4];
    #pragma unroll
    for (int r = 0; r < 4; ++r) {
        if (!LAST) {
            float s = ss[r];
            s += __shfl_xor(s, 1);
            s += __shfl_xor(s, 2);
            s += __shfl_xor(s, 4);
            s += __shfl_xor(s, 8);
            scale[r] = 1.0f / fmaxf(sqrtf(s), 1e-12f);
        } else {
            scale[r] = 1.0f;
        }
    }

    #pragma unroll
    for (int ct = 0; ct < NCT; ++ct) {
        #pragma unroll
        for (int r = 0; r < 4; ++r) {
            int row = n0 + q * 4 + r;
            if (row < N_NODES) {
                float v = acc[ct][r] * scale[r];
                if (LAST)
                    ((float*)out_)[(size_t)row * Dout + ct * 16 + l15] = v;
                else
                    ((unsigned short*)out_)[(size_t)row * Dout + ct * 16 + l15] = f2bf(v);
            }
        }
    }
}

// ---------------- host launch ----------------

extern "C" void kernel_launch(void* const* d_in, const int* in_sizes, int n_in,
                              void* d_out, int out_size, void* d_ws, size_t ws_size,
                              hipStream_t stream) {
    const float* features = (const float*)d_in[0];
    const int* src = (const int*)d_in[1];
    const int* dst = (const int*)d_in[2];
    const float* Ws0 = (const float*)d_in[3];
    const float* Wn0 = (const float*)d_in[4];
    const float* b0  = (const float*)d_in[5];
    const float* Ws1 = (const float*)d_in[6];
    const float* Wn1 = (const float*)d_in[7];
    const float* b1  = (const float*)d_in[8];
    const float* Ws2 = (const float*)d_in[9];
    const float* Wn2 = (const float*)d_in[10];
    const float* b2  = (const float*)d_in[11];
    float* out = (float*)d_out;

    char* ws = (char*)d_ws;
    size_t off = 0;
    auto alloc = [&](size_t bytes) -> void* {
        void* p = ws + off;
        off = (off + bytes + 255) & ~(size_t)255;
        return p;
    };
    int*   cursor   = (int*)alloc((size_t)NBUCKET * 4);
    int*   valid    = (int*)alloc((size_t)NBUCKET * 4);
    int*   gbase    = (int*)alloc((size_t)NBUCKET * 4);
    unsigned int* bucketArr = (unsigned int*)alloc((size_t)NBUCKET * BUCKET_CAP * 4);
    int*   off_beg  = (int*)alloc((size_t)N_NODES * 4);
    int*   off_end  = (int*)alloc((size_t)N_NODES * 4);
    int*   edge_src = (int*)alloc((size_t)(N_EDGES + NBUCKET * 16) * 4);
    float* inv_deg  = (float*)alloc((size_t)N_NODES * 4);
    __hip_bfloat16* fbf = (__hip_bfloat16*)alloc((size_t)N_NODES * 128 * 2);
    __hip_bfloat16* msg = (__hip_bfloat16*)alloc((size_t)N_NODES * 128 * 2);
    __hip_bfloat16* h1  = (__hip_bfloat16*)alloc((size_t)N_NODES * 128 * 2);
    __hip_bfloat16* h2  = (__hip_bfloat16*)alloc((size_t)N_NODES * 128 * 2);
    __hip_bfloat16* frag0 = (__hip_bfloat16*)alloc((size_t)8 * 8 * 64 * 8 * 2);
    __hip_bfloat16* frag1 = (__hip_bfloat16*)alloc((size_t)8 * 8 * 64 * 8 * 2);
    __hip_bfloat16* frag2 = (__hip_bfloat16*)alloc((size_t)4 * 8 * 64 * 8 * 2);

    // prep (frags + f2bf + counter zero), then bucketed CSR v2
    k_prep<<<40 + NF2 + 1, 256, 0, stream>>>(Ws0, Wn0, Ws1, Wn1, Ws2, Wn2,
                                             frag0, frag1, frag2,
                                             (const float2*)features, (unsigned int*)fbf,
                                             cursor, valid);
    k_partA<<<PART_BLOCKS, 256, 0, stream>>>(src, dst, cursor, valid, bucketArr);
    k_scanB<<<1, 256, 0, stream>>>(valid, gbase);
    k_partB<<<NBUCKET, 256, 0, stream>>>(bucketArr, cursor, gbase,
                                         off_beg, off_end, inv_deg, edge_src);

    const int aggGrid = (N_NODES * 64) / 256;  // 12500
    const int gemmGrid = (N_NODES + 63) / 64;  // 782

    // Layer 1
    k_agg<<<aggGrid, 256, 0, stream>>>(fbf, off_beg, off_end, edge_src, inv_deg, msg);
    k_gemm<8, false><<<gemmGrid, 256, 0, stream>>>(fbf, msg, frag0, b0, h1);
    // Layer 2
    k_agg<<<aggGrid, 256, 0, stream>>>(h1, off_beg, off_end, edge_src, inv_deg, msg);
    k_gemm<8, false><<<gemmGrid, 256, 0, stream>>>(h1, msg, frag1, b1, h2);
    // Layer 3
    k_agg<<<aggGrid, 256, 0, stream>>>(h2, off_beg, off_end, edge_src, inv_deg, msg);
    k_gemm<4, true><<<gemmGrid, 256, 0, stream>>>(h2, msg, frag2, b2, out);
}